// Round 10
// baseline (667.147 us; speedup 1.0000x reference)
//
#include <hip/hip_runtime.h>
#include <hip/hip_bf16.h>

#define S_LEN 2048
#define DMODEL 512
#define NHEAD 8
#define DKH 64
#define FFDIM 2048
#define BATCH 2
#define NROWS (BATCH * S_LEN)  // 4096

using bf16 = __hip_bfloat16;
typedef __bf16 bf16x8 __attribute__((ext_vector_type(8)));
typedef float floatx4 __attribute__((ext_vector_type(4)));
typedef float floatx16 __attribute__((ext_vector_type(16)));

// fp32 -> bf16 round-to-nearest-even, branch-free (scalar path, cvt kernel)
__device__ inline unsigned short f2bf_bits(float f) {
    union { float f; unsigned u; } c; c.f = f;
    return (unsigned short)((c.u + 0x7FFFu + ((c.u >> 16) & 1u)) >> 16);
}
__device__ inline unsigned pack2bf(float a, float b) {
    return (unsigned)f2bf_bits(a) | ((unsigned)f2bf_bits(b) << 16);
}
// packed conversion (v_cvt_pk_bf16_f32 on gfx950)
__device__ inline unsigned pk2(float a, float b) {
    float2 f; f.x = a; f.y = b;
    __hip_bfloat162 h = __float22bfloat162_rn(f);
    return *(unsigned*)&h;
}

// async global->LDS, 16 bytes/lane. LDS dest is wave-uniform base + lane*16.
__device__ __forceinline__ void gload_lds16(const bf16* g, bf16* l) {
    __builtin_amdgcn_global_load_lds(
        (const __attribute__((address_space(1))) void*)(const void*)g,
        (__attribute__((address_space(3))) void*)(void*)l, 16, 0, 0);
}

// ---------------------------------------------------------------------------
// fp32 -> bf16 bulk convert, up to 12 segments in one dispatch.
// ---------------------------------------------------------------------------
struct CvtSeg { const float* s; bf16* d; int n4; };
struct CvtDesc { CvtSeg seg[12]; };

__launch_bounds__(256)
__global__ void cvt_f32_bf16(CvtDesc desc) {
    const CvtSeg sg = desc.seg[blockIdx.y];
    const int stride = gridDim.x * 256;
    for (int i = blockIdx.x * 256 + threadIdx.x; i < sg.n4; i += stride) {
        const float4 v = ((const float4*)sg.s)[i];
        uint2 o;
        o.x = pack2bf(v.x, v.y);
        o.y = pack2bf(v.z, v.w);
        ((uint2*)sg.d)[i] = o;
    }
}

// ---------------------------------------------------------------------------
// GEMM v2: C[M,N] = A[M,K] @ W[N,K]^T, BK=64 as two BK=32 panels. Epilogue
// routes 2^shift-wide column slabs to up to 3 outputs with per-slab bias/
// scale; A2 (if set) replaces A for slabs >= a2slab. 4 waves (2x2).
// ---------------------------------------------------------------------------
struct Epi {
    bf16*  outB[3];
    float* outF[3];
    const float* bias[3];
    float scale[3];
    const bf16* A2;   // alternate A source for slabs >= a2slab (or null)
    int a2slab;
    int shift;        // log2(slab width): 9 for 512-wide outputs, 11 for FFN1
    int relu;
};

template <int BM, int BN>
__launch_bounds__(256)
__global__ void gemm2(const bf16* __restrict__ A, const bf16* __restrict__ W,
                      Epi epi, int K)
{
    constexpr int WR = BM / 32;
    constexpr int WC = BN / 32;
    constexpr int SA = BM / 16;
    constexpr int SB = BN / 16;
    constexpr int NG = 2 * (SA + SB);

    __shared__ alignas(16) bf16 As[2][BM][32];
    __shared__ alignas(16) bf16 Bs[2][BN][32];

    const int t = threadIdx.x;
    const int w = t >> 6;
    const int lane = t & 63;
    const int r16 = lane & 15;
    const int quad = lane >> 4;
    const int wm = w >> 1, wn = w & 1;
    const int m0 = blockIdx.x * BM;
    const int n0 = blockIdx.y * BN;

    const bf16* Ause = (epi.A2 && ((n0 >> epi.shift) >= epi.a2slab)) ? epi.A2 : A;

    floatx4 acc[WR][WC];
#pragma unroll
    for (int i = 0; i < WR; i++)
#pragma unroll
        for (int j = 0; j < WC; j++)
#pragma unroll
            for (int e = 0; e < 4; e++) acc[i][j][e] = 0.0f;

    const int grow = lane >> 2;
    const int gcol = (lane & 3) * 8;

    for (int k0 = 0; k0 < K; k0 += 64) {
        __syncthreads();
#pragma unroll
        for (int s = 0; s < NG; s += 4) {
            int sg = s + w;
            int p = 0;
            if (sg >= SA + SB) { p = 1; sg -= SA + SB; }
            const bf16* src;
            bf16* dst;
            if (sg < SA) {
                src = Ause + (size_t)(m0 + sg * 16 + grow) * K + k0 + 32 * p + gcol;
                dst = &As[p][sg * 16][0] + lane * 8;
            } else {
                const int sb = sg - SA;
                src = W + (size_t)(n0 + sb * 16 + grow) * K + k0 + 32 * p + gcol;
                dst = &Bs[p][sb * 16][0] + lane * 8;
            }
            gload_lds16(src, dst);
        }
        __syncthreads();

        bf16x8 af[2][WR], bfr[2][WC];
#pragma unroll
        for (int p = 0; p < 2; p++) {
#pragma unroll
            for (int i = 0; i < WR; i++)
                af[p][i] = *(const bf16x8*)&As[p][wm * (BM / 2) + 16 * i + r16][quad * 8];
#pragma unroll
            for (int j = 0; j < WC; j++)
                bfr[p][j] = *(const bf16x8*)&Bs[p][wn * (BN / 2) + 16 * j + r16][quad * 8];
        }
#pragma unroll
        for (int p = 0; p < 2; p++)
#pragma unroll
            for (int i = 0; i < WR; i++)
#pragma unroll
                for (int j = 0; j < WC; j++)
                    acc[i][j] = __builtin_amdgcn_mfma_f32_16x16x32_bf16(af[p][i], bfr[p][j], acc[i][j], 0, 0, 0);
    }

    const int mask = (1 << epi.shift) - 1;
#pragma unroll
    for (int j = 0; j < WC; j++) {
        const int colb = n0 + wn * (BN / 2) + 16 * j;
        const int sel = __builtin_amdgcn_readfirstlane(colb >> epi.shift);
        const int lcol = (colb & mask) + r16;
        const int ldw = mask + 1;
        const float bv = epi.bias[sel] ? epi.bias[sel][lcol] : 0.0f;
        const float sc = epi.scale[sel];
        bf16* ob = epi.outB[sel];
        float* of = epi.outF[sel];
#pragma unroll
        for (int i = 0; i < WR; i++) {
            const int rowb = m0 + wm * (BM / 2) + 16 * i + 4 * quad;
#pragma unroll
            for (int e = 0; e < 4; e++) {
                float v = (acc[i][j][e] + bv) * sc;
                if (epi.relu) v = fmaxf(v, 0.0f);
                const size_t idx = (size_t)(rowb + e) * ldw + lcol;
                if (of) of[idx] = v;
                if (ob) ob[idx] = __float2bfloat16(v);
            }
        }
    }
}

// ---------------------------------------------------------------------------
// Flash attention, 32x32x16 MFMA, 4-way key split, 512-thread WGs (8 waves).
//   qgroup = (t>>6)&1 : which 32 queries of the 64-tile this wave owns
//   sp     = t>>7     : key-chunk subsequence (chunks 4*it+sp)
// Grid 512 WGs -> 2 blocks/CU x 8 waves = 4 waves/SIMD (round-9 was 2).
// P's C-layout -> A-layout transform is done IN REGISTERS via lane^32
// shfl_xor of packed-bf16 key groups (no Ps LDS): C key=(r&3)+8(r>>2)+4hi,
// A key=8hi+j; groups of 4 consecutive keys swap across the hi halves.
// LDS: Vt[4][64][PST] (36.9KB), overlaid after the K-loop by the 4-way merge
// scratch Msh[2][3][64][34] (52.2KB) -> smem = 52224 B.
// ---------------------------------------------------------------------------
#define PST 72  // LDS row stride (bf16): 64 + 8, keeps b128 alignment

__launch_bounds__(512, 4)
__global__ void attn_mfma(const bf16* __restrict__ Qh, const bf16* __restrict__ Kh,
                          const bf16* __restrict__ Vh,
                          float* __restrict__ outF, bf16* __restrict__ outB,
                          int causal)
{
    __shared__ alignas(16) char smem[52224];
    typedef bf16 (*VtT)[64][PST];
    VtT Vt = (VtT)smem;                   // [4][64][PST], dead after K-loop
    typedef float (*MshT)[3][64][34];
    MshT Msh = (MshT)smem;                // overlay: [qg][sp-1][lane][34]

    const int t = threadIdx.x;        // 0..511
    const int lane = t & 63;
    const int c32 = lane & 31;
    const int hi = lane >> 5;
    const int sp = t >> 7;            // key split 0..3
    const int qg = (t >> 6) & 1;
    const int pl = t & 127;           // split-local thread id
    const int bh = blockIdx.y;
    const int b = bh >> 3, h = bh & 7;
    const int q0 = blockIdx.x * 64;
    const size_t rowbase = (size_t)b * S_LEN;
    const int hoff = h * DKH;

    // persistent Q B-frags: lane holds Q[q=c32][d=16t+8hi+j]
    bf16x8 qf[4];
    {
        const bf16* qp = Qh + (rowbase + q0 + 32 * qg + c32) * DMODEL + hoff + 8 * hi;
#pragma unroll
        for (int tt = 0; tt < 4; tt++) qf[tt] = *(const bf16x8*)(qp + 16 * tt);
    }

    floatx16 o0, o1;
#pragma unroll
    for (int e = 0; e < 16; e++) { o0[e] = 0.0f; o1[e] = 0.0f; }
    float m = -3e38f, l = 0.0f;

    const int rq = pl & 15;
    const int c8 = ((pl >> 4) & 7) * 8;

    const int nchunk = causal ? (q0 / 64 + 1) : (S_LEN / 64);
    const int nIter = (nchunk + 3) >> 2;

    // K-fragment prefetch registers (this wave's chunks: sp, sp+4, ...)
    bf16x8 kf0[4], kf1[4];
    if (sp < nchunk) {
        const bf16* kp = Kh + (rowbase + sp * 64 + c32) * DMODEL + hoff + 8 * hi;
#pragma unroll
        for (int tt = 0; tt < 4; tt++) {
            kf0[tt] = *(const bf16x8*)(kp + 16 * tt);
            kf1[tt] = *(const bf16x8*)(kp + (size_t)32 * DMODEL + 16 * tt);
        }
    }

    for (int it = 0; it < nIter; it++) {
        const int ch = 4 * it + sp;
        const bool active = ch < nchunk;
        const int kb = ch * 64;
        __syncthreads();   // prior PV reads of Vt done -> safe to overwrite
        if (active) {      // stage V transposed (packed b64 writes)
            union { uint4 u; unsigned short s[8]; } r0, r1, r2, r3;
            const bf16* vb = Vh + (rowbase + kb + 4 * rq) * DMODEL + hoff + c8;
            r0.u = *(const uint4*)(vb);
            r1.u = *(const uint4*)(vb + DMODEL);
            r2.u = *(const uint4*)(vb + 2 * DMODEL);
            r3.u = *(const uint4*)(vb + 3 * DMODEL);
#pragma unroll
            for (int j = 0; j < 8; j++) {
                ushort4 pk = { r0.s[j], r1.s[j], r2.s[j], r3.s[j] };
                *(ushort4*)&Vt[sp][c8 + j][4 * rq] = pk;
            }
        }

        uint2 pgrp[2][4];   // packed P: [s0/s1][key group g] = keys 8g+4hi+0..3

        if (active) {
            floatx16 s0, s1;
#pragma unroll
            for (int e = 0; e < 16; e++) { s0[e] = 0.0f; s1[e] = 0.0f; }
#pragma unroll
            for (int tt = 0; tt < 4; tt++) {
                s0 = __builtin_amdgcn_mfma_f32_32x32x16_bf16(kf0[tt], qf[tt], s0, 0, 0, 0);
                s1 = __builtin_amdgcn_mfma_f32_32x32x16_bf16(kf1[tt], qf[tt], s1, 0, 0, 0);
            }

            // prefetch next chunk's K frags (overlaps softmax + PV below)
            const int chn = ch + 4;
            if (chn < nchunk) {
                const bf16* kp = Kh + (rowbase + chn * 64 + c32) * DMODEL + hoff + 8 * hi;
#pragma unroll
                for (int tt = 0; tt < 4; tt++) {
                    kf0[tt] = *(const bf16x8*)(kp + 16 * tt);
                    kf1[tt] = *(const bf16x8*)(kp + (size_t)32 * DMODEL + 16 * tt);
                }
            }

            if (causal && kb == q0) {
                const int qq = 32 * qg + c32;
#pragma unroll
                for (int r = 0; r < 16; r++) {
                    const int kl = (r & 3) + 8 * (r >> 2) + 4 * hi;
                    if (kl > qq) s0[r] = -3e38f;
                    if (kl + 32 > qq) s1[r] = -3e38f;
                }
            }

            float mc = -3e38f;
#pragma unroll
            for (int r = 0; r < 16; r++) mc = fmaxf(mc, fmaxf(s0[r], s1[r]));
            mc = fmaxf(mc, __shfl_xor(mc, 32, 64));
            const float mold = m;
            const float mn = fmaxf(m, mc);
            const float alpha = __expf(mold - mn);
            m = mn;

            float lc = 0.0f;
#pragma unroll
            for (int g = 0; g < 4; g++) {
                float p0 = __expf(s0[4 * g + 0] - mn), p1 = __expf(s0[4 * g + 1] - mn);
                float p2 = __expf(s0[4 * g + 2] - mn), p3 = __expf(s0[4 * g + 3] - mn);
                lc += (p0 + p1) + (p2 + p3);
                pgrp[0][g].x = pk2(p0, p1); pgrp[0][g].y = pk2(p2, p3);
                p0 = __expf(s1[4 * g + 0] - mn); p1 = __expf(s1[4 * g + 1] - mn);
                p2 = __expf(s1[4 * g + 2] - mn); p3 = __expf(s1[4 * g + 3] - mn);
                lc += (p0 + p1) + (p2 + p3);
                pgrp[1][g].x = pk2(p0, p1); pgrp[1][g].y = pk2(p2, p3);
            }
            lc += __shfl_xor(lc, 32, 64);
            l = l * alpha + lc;

            if (!__all(mn == mold)) {
#pragma unroll
                for (int r = 0; r < 16; r++) {
                    const float a = __shfl(alpha, (r & 3) + 8 * (r >> 2) + 4 * hi, 64);
                    o0[r] *= a; o1[r] *= a;
                }
            }
        }

        __syncthreads();   // Vt[sp] staged by both waves of the split

        if (active) {
            // O += P.V ; P A-frags built in registers via lane^32 exchange
#pragma unroll
            for (int tt = 0; tt < 4; tt++) {
                const int sel = tt >> 1;      // s0 or s1
                const int t2 = tt & 1;        // 16-key step within
                const uint2 ge = pgrp[sel][2 * t2];       // keys 16t2+4hi+0..3
                const uint2 go = pgrp[sel][2 * t2 + 1];   // keys 16t2+8+4hi+0..3
                uint2 swe, swo;
                swe.x = __shfl_xor((int)ge.x, 32, 64); swe.y = __shfl_xor((int)ge.y, 32, 64);
                swo.x = __shfl_xor((int)go.x, 32, 64); swo.y = __shfl_xor((int)go.y, 32, 64);
                union { unsigned u[4]; bf16x8 v; } fr;
                fr.u[0] = hi ? swo.x : ge.x;   // keys 16t2 + 8hi + 0,1
                fr.u[1] = hi ? swo.y : ge.y;   //              + 2,3
                fr.u[2] = hi ? go.x : swe.x;   //              + 4,5
                fr.u[3] = hi ? go.y : swe.y;   //              + 6,7
                const bf16x8 v0 = *(const bf16x8*)&Vt[sp][c32][16 * tt + 8 * hi];
                const bf16x8 v1 = *(const bf16x8*)&Vt[sp][32 + c32][16 * tt + 8 * hi];
                o0 = __builtin_amdgcn_mfma_f32_32x32x16_bf16(fr.v, v0, o0, 0, 0, 0);
                o1 = __builtin_amdgcn_mfma_f32_32x32x16_bf16(fr.v, v1, o1, 0, 0, 0);
            }
        }
    }

    // ---- 4-way split-KV merge: splits 1-3 -> LDS overlay, split 0 combines
    __syncthreads();   // all PV reads of Vt done -> safe to overlay
    if (sp > 0) {
        float* dst = &Msh[qg][sp - 1][lane][0];
        dst[0] = m; dst[1] = l;
#pragma unroll
        for (int r = 0; r < 16; r++) { dst[2 + r] = o0[r]; dst[18 + r] = o1[r]; }
    }
    __syncthreads();
    if (sp == 0) {
        const float* p1 = &Msh[qg][0][lane][0];
        const float* p2 = &Msh[qg][1][lane][0];
        const float* p3 = &Msh[qg][2][lane][0];
        const float m1 = p1[0], l1 = p1[1];
        const float m2 = p2[0], l2 = p2[1];
        const float m3 = p3[0], l3 = p3[1];
        const float mt = fmaxf(fmaxf(m, m1), fmaxf(m2, m3));
        const float sA = __expf(m - mt);
        const float s1c = __expf(m1 - mt);
        const float s2c = __expf(m2 - mt);
        const float s3c = __expf(m3 - mt);
        const float lt = l * sA + l1 * s1c + l2 * s2c + l3 * s3c;
#pragma unroll
        for (int r = 0; r < 16; r++) {
            const int ql = (r & 3) + 8 * (r >> 2) + 4 * hi;
            const float aA = __shfl(sA, ql, 64);
            const float a1 = __shfl(s1c, ql, 64);
            const float a2 = __shfl(s2c, ql, 64);
            const float a3 = __shfl(s3c, ql, 64);
            const float li = 1.0f / __shfl(lt, ql, 64);
            const float v0 = (o0[r] * aA + p1[2 + r] * a1 + p2[2 + r] * a2 + p3[2 + r] * a3) * li;
            const float v1 = (o1[r] * aA + p1[18 + r] * a1 + p2[18 + r] * a2 + p3[18 + r] * a3) * li;
            const size_t idx = (rowbase + q0 + 32 * qg + ql) * DMODEL + hoff + c32;
            if (outF) { outF[idx] = v0; outF[idx + 32] = v1; }
            if (outB) { outB[idx] = __float2bfloat16(v0); outB[idx + 32] = __float2bfloat16(v1); }
        }
    }
}

// ---------------------------------------------------------------------------
// Fused residual + LayerNorm over D=512. One WG (256 thr) per row.
// ---------------------------------------------------------------------------
__launch_bounds__(256)
__global__ void ln_kernel(const float* __restrict__ xmain,
                          const float* __restrict__ resF, const bf16* __restrict__ resB,
                          const float* __restrict__ g, const float* __restrict__ bb,
                          float* __restrict__ outF, bf16* __restrict__ outB)
{
    const int row = blockIdx.x;
    const int t = threadIdx.x;
    const size_t base = (size_t)row * DMODEL;

    float x0 = xmain[base + t];
    float x1 = xmain[base + t + 256];
    if (resF) { x0 += resF[base + t]; x1 += resF[base + t + 256]; }
    if (resB) { x0 += __bfloat162float(resB[base + t]); x1 += __bfloat162float(resB[base + t + 256]); }

    __shared__ float sred[4];
    float s = x0 + x1;
#pragma unroll
    for (int off = 32; off > 0; off >>= 1) s += __shfl_down(s, off);
    if ((t & 63) == 0) sred[t >> 6] = s;
    __syncthreads();
    const float mu = (sred[0] + sred[1] + sred[2] + sred[3]) * (1.0f / DMODEL);

    const float d0 = x0 - mu, d1 = x1 - mu;
    float sv = d0 * d0 + d1 * d1;
#pragma unroll
    for (int off = 32; off > 0; off >>= 1) sv += __shfl_down(sv, off);
    __syncthreads();
    if ((t & 63) == 0) sred[t >> 6] = sv;
    __syncthreads();
    const float var = (sred[0] + sred[1] + sred[2] + sred[3]) * (1.0f / DMODEL);
    const float rstd = rsqrtf(var + 1e-5f);

    const float y0 = d0 * rstd * g[t] + bb[t];
    const float y1 = d1 * rstd * g[t + 256] + bb[t + 256];
    if (outF) { outF[base + t] = y0; outF[base + t + 256] = y1; }
    if (outB) { outB[base + t] = __float2bfloat16(y0); outB[base + t + 256] = __float2bfloat16(y1); }
}

// ---------------------------------------------------------------------------
// Workspace layout (55.5 MB) — see round 5 comment.
// ---------------------------------------------------------------------------
extern "C" void kernel_launch(void* const* d_in, const int* in_sizes, int n_in,
                              void* d_out, int out_size, void* d_ws, size_t ws_size,
                              hipStream_t stream)
{
    const float* x_q       = (const float*)d_in[0];
    const float* x1        = (const float*)d_in[1];
    const float* x2        = (const float*)d_in[2];
    const float* sa_wq     = (const float*)d_in[3];
    const float* sa_bq     = (const float*)d_in[4];
    const float* sa_wk     = (const float*)d_in[5];
    const float* sa_bk     = (const float*)d_in[6];
    const float* sa_wv     = (const float*)d_in[7];
    const float* sa_bv     = (const float*)d_in[8];
    const float* ln1_g     = (const float*)d_in[9];
    const float* ln1_b     = (const float*)d_in[10];
    const float* mha_in_w  = (const float*)d_in[11];
    const float* mha_in_b  = (const float*)d_in[12];
    const float* mha_out_w = (const float*)d_in[13];
    const float* mha_out_b = (const float*)d_in[14];
    const float* ln2_g     = (const float*)d_in[15];
    const float* ln2_b     = (const float*)d_in[16];
    const float* ffn_w1    = (const float*)d_in[17];
    const float* ffn_b1    = (const float*)d_in[18];
    const float* ffn_w2    = (const float*)d_in[19];
    const float* ffn_b2    = (const float*)d_in[20];
    const float* ln3_g     = (const float*)d_in[21];
    const float* ln3_b     = (const float*)d_in[22];

    char* ws = (char*)d_ws;
    const size_t MB = 1024 * 1024;
    const size_t KB = 1024;
    bf16*  q16  = (bf16*)(ws + 0 * MB);
    bf16*  k16  = (bf16*)(ws + 4 * MB);
    bf16*  v16  = (bf16*)(ws + 8 * MB);
    bf16*  a16  = (bf16*)(ws + 12 * MB);
    float* tmp  = (float*)(ws + 16 * MB);
    bf16*  y16  = (bf16*)(ws + 24 * MB);
    bf16*  ya16 = (bf16*)(ws + 28 * MB);
    bf16*  ya2  = (bf16*)(ws + 32 * MB);
    bf16*  xq16 = (bf16*)(ws + 36 * MB);
    bf16*  x116 = (bf16*)(ws + 40 * MB);
    bf16*  x216 = (bf16*)(ws + 44 * MB);
    bf16*  w_sa_qkv = (bf16*)(ws + 48 * MB);            // 1.5 MB (3D x D contig)
    bf16*  w_in   = (bf16*)(ws + 49 * MB + 512 * KB);   // 1.5 MB
    bf16*  w_out  = (bf16*)(ws + 51 * MB);              // 0.5 MB
    bf16*  w_f1   = (bf16*)(ws + 51 * MB + 512 * KB);   // 2 MB
    bf16*  w_f2   = (bf16*)(ws + 53 * MB + 512 * KB);   // 2 MB
    bf16*  h16    = (bf16*)(ws + 0 * MB);               // aliases q..a (dead by FFN)

    const int DD = DMODEL * DMODEL;
    CvtDesc cd;
    cd.seg[0]  = { x_q,       xq16,        (NROWS * DMODEL) / 4 };
    cd.seg[1]  = { x1,        x116,        (NROWS * DMODEL) / 4 };
    cd.seg[2]  = { x2,        x216,        (NROWS * DMODEL) / 4 };
    cd.seg[3]  = { sa_wq,     w_sa_qkv,           DD / 4 };
    cd.seg[4]  = { sa_wk,     w_sa_qkv + DD,      DD / 4 };
    cd.seg[5]  = { sa_wv,     w_sa_qkv + 2 * DD,  DD / 4 };
    cd.seg[6]  = { mha_in_w,  w_in,   3 * DD / 4 };
    cd.seg[7]  = { mha_out_w, w_out,  DD / 4 };
    cd.seg[8]  = { ffn_w1,    w_f1,   (FFDIM * DMODEL) / 4 };
    cd.seg[9]  = { ffn_w2,    w_f2,   (FFDIM * DMODEL) / 4 };
    cd.seg[10] = { x_q,       xq16,   0 };
    cd.seg[11] = { x_q,       xq16,   0 };
    cvt_f32_bf16<<<dim3(64, 10), 256, 0, stream>>>(cd);

    const dim3 blk(256);
    const dim3 ablk(512);
    const dim3 agrid(S_LEN / 64, BATCH * NHEAD);   // (32,16) = 512 WGs

    Epi eQKV = {};   // self Q/K/V fused, N=1536 -> q16|k16|v16
    eQKV.outB[0] = q16; eQKV.outB[1] = k16; eQKV.outB[2] = v16;
    eQKV.bias[0] = sa_bq; eQKV.bias[1] = sa_bk; eQKV.bias[2] = sa_bv;
    eQKV.scale[0] = 0.125f; eQKV.scale[1] = 1.0f; eQKV.scale[2] = 1.0f;
    eQKV.shift = 9;

    Epi eX1 = {};    // cross1 Q|K|V fused, N=1536; A=y16 (slab0), A2=x116 (slabs 1-2)
    eX1.outB[0] = q16; eX1.outB[1] = k16; eX1.outB[2] = v16;
    eX1.bias[0] = mha_in_b; eX1.bias[1] = mha_in_b + DMODEL; eX1.bias[2] = mha_in_b + 2 * DMODEL;
    eX1.scale[0] = 0.125f; eX1.scale[1] = 1.0f; eX1.scale[2] = 1.0f;
    eX1.A2 = x116; eX1.a2slab = 1; eX1.shift = 9;

    Epi eX2 = eX1;   // cross2: A=ya16, A2=x216
    eX2.A2 = x216;

    Epi eOut = {};   // out-proj, N=512 -> tmp (fp32)
    eOut.outF[0] = tmp; eOut.bias[0] = mha_out_b; eOut.scale[0] = 1.0f; eOut.shift = 9;

    Epi eF1 = {};    // FFN1, N=2048 -> h16, relu
    eF1.outB[0] = h16; eF1.bias[0] = ffn_b1; eF1.scale[0] = 1.0f;
    eF1.shift = 11; eF1.relu = 1;

    Epi eF2 = {};    // FFN2, N=512 -> tmp (fp32)
    eF2.outF[0] = tmp; eF2.bias[0] = ffn_b2; eF2.scale[0] = 1.0f; eF2.shift = 9;

    // ---- self attention (causal, no out-proj) ----
    gemm2<64, 64><<<dim3(64, 24), blk, 0, stream>>>(xq16, w_sa_qkv, eQKV, DMODEL);
    attn_mfma<<<agrid, ablk, 0, stream>>>(q16, k16, v16, tmp, nullptr, 1);
    ln_kernel<<<NROWS, blk, 0, stream>>>(tmp, x_q, nullptr, ln1_g, ln1_b, nullptr, y16);

    // ---- cross attention 1: q from y, k/v from x1 (one fused GEMM) ----
    gemm2<64, 64><<<dim3(64, 24), blk, 0, stream>>>(y16, w_in, eX1, DMODEL);
    attn_mfma<<<agrid, ablk, 0, stream>>>(q16, k16, v16, nullptr, a16, 0);
    gemm2<64, 64><<<dim3(64, 8), blk, 0, stream>>>(a16, w_out, eOut, DMODEL);
    ln_kernel<<<NROWS, blk, 0, stream>>>(tmp, nullptr, y16, ln2_g, ln2_b, nullptr, ya16);

    // ---- cross attention 2: q from yattn, k/v from x2 ----
    gemm2<64, 64><<<dim3(64, 24), blk, 0, stream>>>(ya16, w_in, eX2, DMODEL);
    attn_mfma<<<agrid, ablk, 0, stream>>>(q16, k16, v16, nullptr, a16, 0);
    gemm2<64, 64><<<dim3(64, 8), blk, 0, stream>>>(a16, w_out, eOut, DMODEL);
    ln_kernel<<<NROWS, blk, 0, stream>>>(tmp, nullptr, ya16, ln2_g, ln2_b, nullptr, ya2);

    // ---- FFN ----
    gemm2<128, 128><<<dim3(32, 16), blk, 0, stream>>>(ya2, w_f1, eF1, DMODEL);
    gemm2<64, 64><<<dim3(64, 8), blk, 0, stream>>>(h16, w_f2, eF2, FFDIM);
    ln_kernel<<<NROWS, blk, 0, stream>>>(tmp, nullptr, ya2, ln3_g, ln3_b, (float*)d_out, nullptr);
}

// Round 11
// 453.107 us; speedup vs baseline: 1.4724x; 1.4724x over previous
//
#include <hip/hip_runtime.h>
#include <hip/hip_bf16.h>

#define S_LEN 2048
#define DMODEL 512
#define NHEAD 8
#define DKH 64
#define FFDIM 2048
#define BATCH 2
#define NROWS (BATCH * S_LEN)  // 4096

using bf16 = __hip_bfloat16;
typedef __bf16 bf16x8 __attribute__((ext_vector_type(8)));
typedef float floatx4 __attribute__((ext_vector_type(4)));
typedef float floatx16 __attribute__((ext_vector_type(16)));

// fp32 -> bf16 round-to-nearest-even, branch-free (scalar path, cvt kernel)
__device__ inline unsigned short f2bf_bits(float f) {
    union { float f; unsigned u; } c; c.f = f;
    return (unsigned short)((c.u + 0x7FFFu + ((c.u >> 16) & 1u)) >> 16);
}
__device__ inline unsigned pack2bf(float a, float b) {
    return (unsigned)f2bf_bits(a) | ((unsigned)f2bf_bits(b) << 16);
}
// packed conversion (v_cvt_pk_bf16_f32 on gfx950)
__device__ inline unsigned pk2(float a, float b) {
    float2 f; f.x = a; f.y = b;
    __hip_bfloat162 h = __float22bfloat162_rn(f);
    return *(unsigned*)&h;
}

// async global->LDS, 16 bytes/lane. LDS dest is wave-uniform base + lane*16.
__device__ __forceinline__ void gload_lds16(const bf16* g, bf16* l) {
    __builtin_amdgcn_global_load_lds(
        (const __attribute__((address_space(1))) void*)(const void*)g,
        (__attribute__((address_space(3))) void*)(void*)l, 16, 0, 0);
}

// ---------------------------------------------------------------------------
// fp32 -> bf16 bulk convert, up to 12 segments in one dispatch.
// ---------------------------------------------------------------------------
struct CvtSeg { const float* s; bf16* d; int n4; };
struct CvtDesc { CvtSeg seg[12]; };

__launch_bounds__(256)
__global__ void cvt_f32_bf16(CvtDesc desc) {
    const CvtSeg sg = desc.seg[blockIdx.y];
    const int stride = gridDim.x * 256;
    for (int i = blockIdx.x * 256 + threadIdx.x; i < sg.n4; i += stride) {
        const float4 v = ((const float4*)sg.s)[i];
        uint2 o;
        o.x = pack2bf(v.x, v.y);
        o.y = pack2bf(v.z, v.w);
        ((uint2*)sg.d)[i] = o;
    }
}

// ---------------------------------------------------------------------------
// GEMM v2: C[M,N] = A[M,K] @ W[N,K]^T, BK=64 as two BK=32 panels. Epilogue
// routes 2^shift-wide column slabs to up to 3 outputs with per-slab bias/
// scale; A2 (if set) replaces A for slabs >= a2slab. 4 waves (2x2).
// ---------------------------------------------------------------------------
struct Epi {
    bf16*  outB[3];
    float* outF[3];
    const float* bias[3];
    float scale[3];
    const bf16* A2;   // alternate A source for slabs >= a2slab (or null)
    int a2slab;
    int shift;        // log2(slab width): 9 for 512-wide outputs, 11 for FFN1
    int relu;
};

template <int BM, int BN>
__launch_bounds__(256)
__global__ void gemm2(const bf16* __restrict__ A, const bf16* __restrict__ W,
                      Epi epi, int K)
{
    constexpr int WR = BM / 32;
    constexpr int WC = BN / 32;
    constexpr int SA = BM / 16;
    constexpr int SB = BN / 16;
    constexpr int NG = 2 * (SA + SB);

    __shared__ alignas(16) bf16 As[2][BM][32];
    __shared__ alignas(16) bf16 Bs[2][BN][32];

    const int t = threadIdx.x;
    const int w = t >> 6;
    const int lane = t & 63;
    const int r16 = lane & 15;
    const int quad = lane >> 4;
    const int wm = w >> 1, wn = w & 1;
    const int m0 = blockIdx.x * BM;
    const int n0 = blockIdx.y * BN;

    const bf16* Ause = (epi.A2 && ((n0 >> epi.shift) >= epi.a2slab)) ? epi.A2 : A;

    floatx4 acc[WR][WC];
#pragma unroll
    for (int i = 0; i < WR; i++)
#pragma unroll
        for (int j = 0; j < WC; j++)
#pragma unroll
            for (int e = 0; e < 4; e++) acc[i][j][e] = 0.0f;

    const int grow = lane >> 2;
    const int gcol = (lane & 3) * 8;

    for (int k0 = 0; k0 < K; k0 += 64) {
        __syncthreads();
#pragma unroll
        for (int s = 0; s < NG; s += 4) {
            int sg = s + w;
            int p = 0;
            if (sg >= SA + SB) { p = 1; sg -= SA + SB; }
            const bf16* src;
            bf16* dst;
            if (sg < SA) {
                src = Ause + (size_t)(m0 + sg * 16 + grow) * K + k0 + 32 * p + gcol;
                dst = &As[p][sg * 16][0] + lane * 8;
            } else {
                const int sb = sg - SA;
                src = W + (size_t)(n0 + sb * 16 + grow) * K + k0 + 32 * p + gcol;
                dst = &Bs[p][sb * 16][0] + lane * 8;
            }
            gload_lds16(src, dst);
        }
        __syncthreads();

        bf16x8 af[2][WR], bfr[2][WC];
#pragma unroll
        for (int p = 0; p < 2; p++) {
#pragma unroll
            for (int i = 0; i < WR; i++)
                af[p][i] = *(const bf16x8*)&As[p][wm * (BM / 2) + 16 * i + r16][quad * 8];
#pragma unroll
            for (int j = 0; j < WC; j++)
                bfr[p][j] = *(const bf16x8*)&Bs[p][wn * (BN / 2) + 16 * j + r16][quad * 8];
        }
#pragma unroll
        for (int p = 0; p < 2; p++)
#pragma unroll
            for (int i = 0; i < WR; i++)
#pragma unroll
                for (int j = 0; j < WC; j++)
                    acc[i][j] = __builtin_amdgcn_mfma_f32_16x16x32_bf16(af[p][i], bfr[p][j], acc[i][j], 0, 0, 0);
    }

    const int mask = (1 << epi.shift) - 1;
#pragma unroll
    for (int j = 0; j < WC; j++) {
        const int colb = n0 + wn * (BN / 2) + 16 * j;
        const int sel = __builtin_amdgcn_readfirstlane(colb >> epi.shift);
        const int lcol = (colb & mask) + r16;
        const int ldw = mask + 1;
        const float bv = epi.bias[sel] ? epi.bias[sel][lcol] : 0.0f;
        const float sc = epi.scale[sel];
        bf16* ob = epi.outB[sel];
        float* of = epi.outF[sel];
#pragma unroll
        for (int i = 0; i < WR; i++) {
            const int rowb = m0 + wm * (BM / 2) + 16 * i + 4 * quad;
#pragma unroll
            for (int e = 0; e < 4; e++) {
                float v = (acc[i][j][e] + bv) * sc;
                if (epi.relu) v = fmaxf(v, 0.0f);
                const size_t idx = (size_t)(rowb + e) * ldw + lcol;
                if (of) of[idx] = v;
                if (ob) ob[idx] = __float2bfloat16(v);
            }
        }
    }
}

// ---------------------------------------------------------------------------
// Flash attention, 32x32x16 MFMA, 4-way key split, 512-thread WGs (8 waves).
// ROUND 11: __launch_bounds__(512) with NO min-occupancy arg. Round 10's
// (512,4) forced VGPR_Count=64 (observed) -> ~50 VGPR/wave spilled to scratch
// (WRITE_SIZE 4->298 MB, attn 67->145us). With ~110-130 VGPRs the HW gets
// 2 blocks/CU = 4 waves/SIMD naturally.
// P's C-layout -> A-layout transform via lane^32 shfl_xor (no Ps LDS).
// LDS: Vt[4][64][PST] (36.9KB) overlaid after K-loop by Msh merge (52.2KB).
// ---------------------------------------------------------------------------
#define PST 72  // LDS row stride (bf16): 64 + 8, keeps b128 alignment

__launch_bounds__(512)
__global__ void attn_mfma(const bf16* __restrict__ Qh, const bf16* __restrict__ Kh,
                          const bf16* __restrict__ Vh,
                          float* __restrict__ outF, bf16* __restrict__ outB,
                          int causal)
{
    __shared__ alignas(16) char smem[52224];
    typedef bf16 (*VtT)[64][PST];
    VtT Vt = (VtT)smem;                   // [4][64][PST], dead after K-loop
    typedef float (*MshT)[3][64][34];
    MshT Msh = (MshT)smem;                // overlay: [qg][sp-1][lane][34]

    const int t = threadIdx.x;        // 0..511
    const int lane = t & 63;
    const int c32 = lane & 31;
    const int hi = lane >> 5;
    const int sp = t >> 7;            // key split 0..3
    const int qg = (t >> 6) & 1;
    const int pl = t & 127;           // split-local thread id
    const int bh = blockIdx.y;
    const int b = bh >> 3, h = bh & 7;
    const int q0 = blockIdx.x * 64;
    const size_t rowbase = (size_t)b * S_LEN;
    const int hoff = h * DKH;

    // persistent Q B-frags: lane holds Q[q=c32][d=16t+8hi+j]
    bf16x8 qf[4];
    {
        const bf16* qp = Qh + (rowbase + q0 + 32 * qg + c32) * DMODEL + hoff + 8 * hi;
#pragma unroll
        for (int tt = 0; tt < 4; tt++) qf[tt] = *(const bf16x8*)(qp + 16 * tt);
    }

    floatx16 o0, o1;
#pragma unroll
    for (int e = 0; e < 16; e++) { o0[e] = 0.0f; o1[e] = 0.0f; }
    float m = -3e38f, l = 0.0f;

    const int rq = pl & 15;
    const int c8 = ((pl >> 4) & 7) * 8;

    const int nchunk = causal ? (q0 / 64 + 1) : (S_LEN / 64);
    const int nIter = (nchunk + 3) >> 2;

    // K-fragment prefetch registers (this wave's chunks: sp, sp+4, ...)
    bf16x8 kf0[4], kf1[4];
    if (sp < nchunk) {
        const bf16* kp = Kh + (rowbase + sp * 64 + c32) * DMODEL + hoff + 8 * hi;
#pragma unroll
        for (int tt = 0; tt < 4; tt++) {
            kf0[tt] = *(const bf16x8*)(kp + 16 * tt);
            kf1[tt] = *(const bf16x8*)(kp + (size_t)32 * DMODEL + 16 * tt);
        }
    }

    for (int it = 0; it < nIter; it++) {
        const int ch = 4 * it + sp;
        const bool active = ch < nchunk;
        const int kb = ch * 64;
        __syncthreads();   // prior PV reads of Vt done -> safe to overwrite
        if (active) {      // stage V transposed (packed b64 writes)
            union { uint4 u; unsigned short s[8]; } r0, r1, r2, r3;
            const bf16* vb = Vh + (rowbase + kb + 4 * rq) * DMODEL + hoff + c8;
            r0.u = *(const uint4*)(vb);
            r1.u = *(const uint4*)(vb + DMODEL);
            r2.u = *(const uint4*)(vb + 2 * DMODEL);
            r3.u = *(const uint4*)(vb + 3 * DMODEL);
#pragma unroll
            for (int j = 0; j < 8; j++) {
                ushort4 pk = { r0.s[j], r1.s[j], r2.s[j], r3.s[j] };
                *(ushort4*)&Vt[sp][c8 + j][4 * rq] = pk;
            }
        }

        uint2 pgrp[2][4];   // packed P: [s0/s1][key group g] = keys 8g+4hi+0..3

        if (active) {
            floatx16 s0, s1;
#pragma unroll
            for (int e = 0; e < 16; e++) { s0[e] = 0.0f; s1[e] = 0.0f; }
#pragma unroll
            for (int tt = 0; tt < 4; tt++) {
                s0 = __builtin_amdgcn_mfma_f32_32x32x16_bf16(kf0[tt], qf[tt], s0, 0, 0, 0);
                s1 = __builtin_amdgcn_mfma_f32_32x32x16_bf16(kf1[tt], qf[tt], s1, 0, 0, 0);
            }

            // prefetch next chunk's K frags (overlaps softmax + PV below)
            const int chn = ch + 4;
            if (chn < nchunk) {
                const bf16* kp = Kh + (rowbase + chn * 64 + c32) * DMODEL + hoff + 8 * hi;
#pragma unroll
                for (int tt = 0; tt < 4; tt++) {
                    kf0[tt] = *(const bf16x8*)(kp + 16 * tt);
                    kf1[tt] = *(const bf16x8*)(kp + (size_t)32 * DMODEL + 16 * tt);
                }
            }

            if (causal && kb == q0) {
                const int qq = 32 * qg + c32;
#pragma unroll
                for (int r = 0; r < 16; r++) {
                    const int kl = (r & 3) + 8 * (r >> 2) + 4 * hi;
                    if (kl > qq) s0[r] = -3e38f;
                    if (kl + 32 > qq) s1[r] = -3e38f;
                }
            }

            float mc = -3e38f;
#pragma unroll
            for (int r = 0; r < 16; r++) mc = fmaxf(mc, fmaxf(s0[r], s1[r]));
            mc = fmaxf(mc, __shfl_xor(mc, 32, 64));
            const float mold = m;
            const float mn = fmaxf(m, mc);
            const float alpha = __expf(mold - mn);
            m = mn;

            float lc = 0.0f;
#pragma unroll
            for (int g = 0; g < 4; g++) {
                float p0 = __expf(s0[4 * g + 0] - mn), p1 = __expf(s0[4 * g + 1] - mn);
                float p2 = __expf(s0[4 * g + 2] - mn), p3 = __expf(s0[4 * g + 3] - mn);
                lc += (p0 + p1) + (p2 + p3);
                pgrp[0][g].x = pk2(p0, p1); pgrp[0][g].y = pk2(p2, p3);
                p0 = __expf(s1[4 * g + 0] - mn); p1 = __expf(s1[4 * g + 1] - mn);
                p2 = __expf(s1[4 * g + 2] - mn); p3 = __expf(s1[4 * g + 3] - mn);
                lc += (p0 + p1) + (p2 + p3);
                pgrp[1][g].x = pk2(p0, p1); pgrp[1][g].y = pk2(p2, p3);
            }
            lc += __shfl_xor(lc, 32, 64);
            l = l * alpha + lc;

            if (!__all(mn == mold)) {
#pragma unroll
                for (int r = 0; r < 16; r++) {
                    const float a = __shfl(alpha, (r & 3) + 8 * (r >> 2) + 4 * hi, 64);
                    o0[r] *= a; o1[r] *= a;
                }
            }
        }

        __syncthreads();   // Vt[sp] staged by both waves of the split

        if (active) {
            // O += P.V ; P A-frags built in registers via lane^32 exchange
#pragma unroll
            for (int tt = 0; tt < 4; tt++) {
                const int sel = tt >> 1;      // s0 or s1
                const int t2 = tt & 1;        // 16-key step within
                const uint2 ge = pgrp[sel][2 * t2];       // keys 16t2+4hi+0..3
                const uint2 go = pgrp[sel][2 * t2 + 1];   // keys 16t2+8+4hi+0..3
                uint2 swe, swo;
                swe.x = __shfl_xor((int)ge.x, 32, 64); swe.y = __shfl_xor((int)ge.y, 32, 64);
                swo.x = __shfl_xor((int)go.x, 32, 64); swo.y = __shfl_xor((int)go.y, 32, 64);
                union { unsigned u[4]; bf16x8 v; } fr;
                fr.u[0] = hi ? swo.x : ge.x;   // keys 16t2 + 8hi + 0,1
                fr.u[1] = hi ? swo.y : ge.y;   //              + 2,3
                fr.u[2] = hi ? go.x : swe.x;   //              + 4,5
                fr.u[3] = hi ? go.y : swe.y;   //              + 6,7
                const bf16x8 v0 = *(const bf16x8*)&Vt[sp][c32][16 * tt + 8 * hi];
                const bf16x8 v1 = *(const bf16x8*)&Vt[sp][32 + c32][16 * tt + 8 * hi];
                o0 = __builtin_amdgcn_mfma_f32_32x32x16_bf16(fr.v, v0, o0, 0, 0, 0);
                o1 = __builtin_amdgcn_mfma_f32_32x32x16_bf16(fr.v, v1, o1, 0, 0, 0);
            }
        }
    }

    // ---- 4-way split-KV merge: splits 1-3 -> LDS overlay, split 0 combines
    __syncthreads();   // all PV reads of Vt done -> safe to overlay
    if (sp > 0) {
        float* dst = &Msh[qg][sp - 1][lane][0];
        dst[0] = m; dst[1] = l;
#pragma unroll
        for (int r = 0; r < 16; r++) { dst[2 + r] = o0[r]; dst[18 + r] = o1[r]; }
    }
    __syncthreads();
    if (sp == 0) {
        const float* p1 = &Msh[qg][0][lane][0];
        const float* p2 = &Msh[qg][1][lane][0];
        const float* p3 = &Msh[qg][2][lane][0];
        const float m1 = p1[0], l1 = p1[1];
        const float m2 = p2[0], l2 = p2[1];
        const float m3 = p3[0], l3 = p3[1];
        const float mt = fmaxf(fmaxf(m, m1), fmaxf(m2, m3));
        const float sA = __expf(m - mt);
        const float s1c = __expf(m1 - mt);
        const float s2c = __expf(m2 - mt);
        const float s3c = __expf(m3 - mt);
        const float lt = l * sA + l1 * s1c + l2 * s2c + l3 * s3c;
#pragma unroll
        for (int r = 0; r < 16; r++) {
            const int ql = (r & 3) + 8 * (r >> 2) + 4 * hi;
            const float aA = __shfl(sA, ql, 64);
            const float a1 = __shfl(s1c, ql, 64);
            const float a2 = __shfl(s2c, ql, 64);
            const float a3 = __shfl(s3c, ql, 64);
            const float li = 1.0f / __shfl(lt, ql, 64);
            const float v0 = (o0[r] * aA + p1[2 + r] * a1 + p2[2 + r] * a2 + p3[2 + r] * a3) * li;
            const float v1 = (o1[r] * aA + p1[18 + r] * a1 + p2[18 + r] * a2 + p3[18 + r] * a3) * li;
            const size_t idx = (rowbase + q0 + 32 * qg + ql) * DMODEL + hoff + c32;
            if (outF) { outF[idx] = v0; outF[idx + 32] = v1; }
            if (outB) { outB[idx] = __float2bfloat16(v0); outB[idx + 32] = __float2bfloat16(v1); }
        }
    }
}

// ---------------------------------------------------------------------------
// Fused residual + LayerNorm over D=512. One WG (256 thr) per row.
// ---------------------------------------------------------------------------
__launch_bounds__(256)
__global__ void ln_kernel(const float* __restrict__ xmain,
                          const float* __restrict__ resF, const bf16* __restrict__ resB,
                          const float* __restrict__ g, const float* __restrict__ bb,
                          float* __restrict__ outF, bf16* __restrict__ outB)
{
    const int row = blockIdx.x;
    const int t = threadIdx.x;
    const size_t base = (size_t)row * DMODEL;

    float x0 = xmain[base + t];
    float x1 = xmain[base + t + 256];
    if (resF) { x0 += resF[base + t]; x1 += resF[base + t + 256]; }
    if (resB) { x0 += __bfloat162float(resB[base + t]); x1 += __bfloat162float(resB[base + t + 256]); }

    __shared__ float sred[4];
    float s = x0 + x1;
#pragma unroll
    for (int off = 32; off > 0; off >>= 1) s += __shfl_down(s, off);
    if ((t & 63) == 0) sred[t >> 6] = s;
    __syncthreads();
    const float mu = (sred[0] + sred[1] + sred[2] + sred[3]) * (1.0f / DMODEL);

    const float d0 = x0 - mu, d1 = x1 - mu;
    float sv = d0 * d0 + d1 * d1;
#pragma unroll
    for (int off = 32; off > 0; off >>= 1) sv += __shfl_down(sv, off);
    __syncthreads();
    if ((t & 63) == 0) sred[t >> 6] = sv;
    __syncthreads();
    const float var = (sred[0] + sred[1] + sred[2] + sred[3]) * (1.0f / DMODEL);
    const float rstd = rsqrtf(var + 1e-5f);

    const float y0 = d0 * rstd * g[t] + bb[t];
    const float y1 = d1 * rstd * g[t + 256] + bb[t + 256];
    if (outF) { outF[base + t] = y0; outF[base + t + 256] = y1; }
    if (outB) { outB[base + t] = __float2bfloat16(y0); outB[base + t + 256] = __float2bfloat16(y1); }
}

// ---------------------------------------------------------------------------
// Workspace layout (55.5 MB) — see round 5 comment.
// ---------------------------------------------------------------------------
extern "C" void kernel_launch(void* const* d_in, const int* in_sizes, int n_in,
                              void* d_out, int out_size, void* d_ws, size_t ws_size,
                              hipStream_t stream)
{
    const float* x_q       = (const float*)d_in[0];
    const float* x1        = (const float*)d_in[1];
    const float* x2        = (const float*)d_in[2];
    const float* sa_wq     = (const float*)d_in[3];
    const float* sa_bq     = (const float*)d_in[4];
    const float* sa_wk     = (const float*)d_in[5];
    const float* sa_bk     = (const float*)d_in[6];
    const float* sa_wv     = (const float*)d_in[7];
    const float* sa_bv     = (const float*)d_in[8];
    const float* ln1_g     = (const float*)d_in[9];
    const float* ln1_b     = (const float*)d_in[10];
    const float* mha_in_w  = (const float*)d_in[11];
    const float* mha_in_b  = (const float*)d_in[12];
    const float* mha_out_w = (const float*)d_in[13];
    const float* mha_out_b = (const float*)d_in[14];
    const float* ln2_g     = (const float*)d_in[15];
    const float* ln2_b     = (const float*)d_in[16];
    const float* ffn_w1    = (const float*)d_in[17];
    const float* ffn_b1    = (const float*)d_in[18];
    const float* ffn_w2    = (const float*)d_in[19];
    const float* ffn_b2    = (const float*)d_in[20];
    const float* ln3_g     = (const float*)d_in[21];
    const float* ln3_b     = (const float*)d_in[22];

    char* ws = (char*)d_ws;
    const size_t MB = 1024 * 1024;
    const size_t KB = 1024;
    bf16*  q16  = (bf16*)(ws + 0 * MB);
    bf16*  k16  = (bf16*)(ws + 4 * MB);
    bf16*  v16  = (bf16*)(ws + 8 * MB);
    bf16*  a16  = (bf16*)(ws + 12 * MB);
    float* tmp  = (float*)(ws + 16 * MB);
    bf16*  y16  = (bf16*)(ws + 24 * MB);
    bf16*  ya16 = (bf16*)(ws + 28 * MB);
    bf16*  ya2  = (bf16*)(ws + 32 * MB);
    bf16*  xq16 = (bf16*)(ws + 36 * MB);
    bf16*  x116 = (bf16*)(ws + 40 * MB);
    bf16*  x216 = (bf16*)(ws + 44 * MB);
    bf16*  w_sa_qkv = (bf16*)(ws + 48 * MB);            // 1.5 MB (3D x D contig)
    bf16*  w_in   = (bf16*)(ws + 49 * MB + 512 * KB);   // 1.5 MB
    bf16*  w_out  = (bf16*)(ws + 51 * MB);              // 0.5 MB
    bf16*  w_f1   = (bf16*)(ws + 51 * MB + 512 * KB);   // 2 MB
    bf16*  w_f2   = (bf16*)(ws + 53 * MB + 512 * KB);   // 2 MB
    bf16*  h16    = (bf16*)(ws + 0 * MB);               // aliases q..a (dead by FFN)

    const int DD = DMODEL * DMODEL;
    CvtDesc cd;
    cd.seg[0]  = { x_q,       xq16,        (NROWS * DMODEL) / 4 };
    cd.seg[1]  = { x1,        x116,        (NROWS * DMODEL) / 4 };
    cd.seg[2]  = { x2,        x216,        (NROWS * DMODEL) / 4 };
    cd.seg[3]  = { sa_wq,     w_sa_qkv,           DD / 4 };
    cd.seg[4]  = { sa_wk,     w_sa_qkv + DD,      DD / 4 };
    cd.seg[5]  = { sa_wv,     w_sa_qkv + 2 * DD,  DD / 4 };
    cd.seg[6]  = { mha_in_w,  w_in,   3 * DD / 4 };
    cd.seg[7]  = { mha_out_w, w_out,  DD / 4 };
    cd.seg[8]  = { ffn_w1,    w_f1,   (FFDIM * DMODEL) / 4 };
    cd.seg[9]  = { ffn_w2,    w_f2,   (FFDIM * DMODEL) / 4 };
    cd.seg[10] = { x_q,       xq16,   0 };
    cd.seg[11] = { x_q,       xq16,   0 };
    cvt_f32_bf16<<<dim3(64, 10), 256, 0, stream>>>(cd);

    const dim3 blk(256);
    const dim3 ablk(512);
    const dim3 agrid(S_LEN / 64, BATCH * NHEAD);   // (32,16) = 512 WGs

    Epi eQKV = {};   // self Q/K/V fused, N=1536 -> q16|k16|v16
    eQKV.outB[0] = q16; eQKV.outB[1] = k16; eQKV.outB[2] = v16;
    eQKV.bias[0] = sa_bq; eQKV.bias[1] = sa_bk; eQKV.bias[2] = sa_bv;
    eQKV.scale[0] = 0.125f; eQKV.scale[1] = 1.0f; eQKV.scale[2] = 1.0f;
    eQKV.shift = 9;

    Epi eX1 = {};    // cross1 Q|K|V fused, N=1536; A=y16 (slab0), A2=x116 (slabs 1-2)
    eX1.outB[0] = q16; eX1.outB[1] = k16; eX1.outB[2] = v16;
    eX1.bias[0] = mha_in_b; eX1.bias[1] = mha_in_b + DMODEL; eX1.bias[2] = mha_in_b + 2 * DMODEL;
    eX1.scale[0] = 0.125f; eX1.scale[1] = 1.0f; eX1.scale[2] = 1.0f;
    eX1.A2 = x116; eX1.a2slab = 1; eX1.shift = 9;

    Epi eX2 = eX1;   // cross2: A=ya16, A2=x216
    eX2.A2 = x216;

    Epi eOut = {};   // out-proj, N=512 -> tmp (fp32)
    eOut.outF[0] = tmp; eOut.bias[0] = mha_out_b; eOut.scale[0] = 1.0f; eOut.shift = 9;

    Epi eF1 = {};    // FFN1, N=2048 -> h16, relu
    eF1.outB[0] = h16; eF1.bias[0] = ffn_b1; eF1.scale[0] = 1.0f;
    eF1.shift = 11; eF1.relu = 1;

    Epi eF2 = {};    // FFN2, N=512 -> tmp (fp32)
    eF2.outF[0] = tmp; eF2.bias[0] = ffn_b2; eF2.scale[0] = 1.0f; eF2.shift = 9;

    // ---- self attention (causal, no out-proj) ----
    gemm2<64, 64><<<dim3(64, 24), blk, 0, stream>>>(xq16, w_sa_qkv, eQKV, DMODEL);
    attn_mfma<<<agrid, ablk, 0, stream>>>(q16, k16, v16, tmp, nullptr, 1);
    ln_kernel<<<NROWS, blk, 0, stream>>>(tmp, x_q, nullptr, ln1_g, ln1_b, nullptr, y16);

    // ---- cross attention 1: q from y, k/v from x1 (one fused GEMM) ----
    gemm2<64, 64><<<dim3(64, 24), blk, 0, stream>>>(y16, w_in, eX1, DMODEL);
    attn_mfma<<<agrid, ablk, 0, stream>>>(q16, k16, v16, nullptr, a16, 0);
    gemm2<64, 64><<<dim3(64, 8), blk, 0, stream>>>(a16, w_out, eOut, DMODEL);
    ln_kernel<<<NROWS, blk, 0, stream>>>(tmp, nullptr, y16, ln2_g, ln2_b, nullptr, ya16);

    // ---- cross attention 2: q from yattn, k/v from x2 ----
    gemm2<64, 64><<<dim3(64, 24), blk, 0, stream>>>(ya16, w_in, eX2, DMODEL);
    attn_mfma<<<agrid, ablk, 0, stream>>>(q16, k16, v16, nullptr, a16, 0);
    gemm2<64, 64><<<dim3(64, 8), blk, 0, stream>>>(a16, w_out, eOut, DMODEL);
    ln_kernel<<<NROWS, blk, 0, stream>>>(tmp, nullptr, ya16, ln2_g, ln2_b, nullptr, ya2);

    // ---- FFN ----
    gemm2<128, 128><<<dim3(32, 16), blk, 0, stream>>>(ya2, w_f1, eF1, DMODEL);
    gemm2<64, 64><<<dim3(64, 8), blk, 0, stream>>>(h16, w_f2, eF2, FFDIM);
    ln_kernel<<<NROWS, blk, 0, stream>>>(tmp, nullptr, ya2, ln3_g, ln3_b, (float*)d_out, nullptr);
}

// Round 12
// 448.034 us; speedup vs baseline: 1.4891x; 1.0113x over previous
//
#include <hip/hip_runtime.h>
#include <hip/hip_bf16.h>

#define S_LEN 2048
#define DMODEL 512
#define NHEAD 8
#define DKH 64
#define FFDIM 2048
#define BATCH 2
#define NROWS (BATCH * S_LEN)  // 4096

using bf16 = __hip_bfloat16;
typedef __bf16 bf16x8 __attribute__((ext_vector_type(8)));
typedef float floatx4 __attribute__((ext_vector_type(4)));
typedef float floatx16 __attribute__((ext_vector_type(16)));

// fp32 -> bf16 round-to-nearest-even, branch-free (scalar path, cvt kernel)
__device__ inline unsigned short f2bf_bits(float f) {
    union { float f; unsigned u; } c; c.f = f;
    return (unsigned short)((c.u + 0x7FFFu + ((c.u >> 16) & 1u)) >> 16);
}
__device__ inline unsigned pack2bf(float a, float b) {
    return (unsigned)f2bf_bits(a) | ((unsigned)f2bf_bits(b) << 16);
}
// packed conversion (v_cvt_pk_bf16_f32 on gfx950)
__device__ inline unsigned pk2(float a, float b) {
    float2 f; f.x = a; f.y = b;
    __hip_bfloat162 h = __float22bfloat162_rn(f);
    return *(unsigned*)&h;
}

// async global->LDS, 16 bytes/lane. LDS dest is wave-uniform base + lane*16.
__device__ __forceinline__ void gload_lds16(const bf16* g, bf16* l) {
    __builtin_amdgcn_global_load_lds(
        (const __attribute__((address_space(1))) void*)(const void*)g,
        (__attribute__((address_space(3))) void*)(void*)l, 16, 0, 0);
}

// ---------------------------------------------------------------------------
// fp32 -> bf16 bulk convert, up to 12 segments in one dispatch.
// ---------------------------------------------------------------------------
struct CvtSeg { const float* s; bf16* d; int n4; };
struct CvtDesc { CvtSeg seg[12]; };

__launch_bounds__(256)
__global__ void cvt_f32_bf16(CvtDesc desc) {
    const CvtSeg sg = desc.seg[blockIdx.y];
    const int stride = gridDim.x * 256;
    for (int i = blockIdx.x * 256 + threadIdx.x; i < sg.n4; i += stride) {
        const float4 v = ((const float4*)sg.s)[i];
        uint2 o;
        o.x = pack2bf(v.x, v.y);
        o.y = pack2bf(v.z, v.w);
        ((uint2*)sg.d)[i] = o;
    }
}

// ---------------------------------------------------------------------------
// GEMM v2: C[M,N] = A[M,K] @ W[N,K]^T, BK=64 as two BK=32 panels. Epilogue
// routes 2^shift-wide column slabs to up to 3 outputs with per-slab bias/
// scale; A2 (if set) replaces A for slabs >= a2slab. 4 waves (2x2).
// ---------------------------------------------------------------------------
struct Epi {
    bf16*  outB[3];
    float* outF[3];
    const float* bias[3];
    float scale[3];
    const bf16* A2;   // alternate A source for slabs >= a2slab (or null)
    int a2slab;
    int shift;        // log2(slab width): 9 for 512-wide outputs, 11 for FFN1
    int relu;
};

template <int BM, int BN>
__launch_bounds__(256)
__global__ void gemm2(const bf16* __restrict__ A, const bf16* __restrict__ W,
                      Epi epi, int K)
{
    constexpr int WR = BM / 32;
    constexpr int WC = BN / 32;
    constexpr int SA = BM / 16;
    constexpr int SB = BN / 16;
    constexpr int NG = 2 * (SA + SB);

    __shared__ alignas(16) bf16 As[2][BM][32];
    __shared__ alignas(16) bf16 Bs[2][BN][32];

    const int t = threadIdx.x;
    const int w = t >> 6;
    const int lane = t & 63;
    const int r16 = lane & 15;
    const int quad = lane >> 4;
    const int wm = w >> 1, wn = w & 1;
    const int m0 = blockIdx.x * BM;
    const int n0 = blockIdx.y * BN;

    const bf16* Ause = (epi.A2 && ((n0 >> epi.shift) >= epi.a2slab)) ? epi.A2 : A;

    floatx4 acc[WR][WC];
#pragma unroll
    for (int i = 0; i < WR; i++)
#pragma unroll
        for (int j = 0; j < WC; j++)
#pragma unroll
            for (int e = 0; e < 4; e++) acc[i][j][e] = 0.0f;

    const int grow = lane >> 2;
    const int gcol = (lane & 3) * 8;

    for (int k0 = 0; k0 < K; k0 += 64) {
        __syncthreads();
#pragma unroll
        for (int s = 0; s < NG; s += 4) {
            int sg = s + w;
            int p = 0;
            if (sg >= SA + SB) { p = 1; sg -= SA + SB; }
            const bf16* src;
            bf16* dst;
            if (sg < SA) {
                src = Ause + (size_t)(m0 + sg * 16 + grow) * K + k0 + 32 * p + gcol;
                dst = &As[p][sg * 16][0] + lane * 8;
            } else {
                const int sb = sg - SA;
                src = W + (size_t)(n0 + sb * 16 + grow) * K + k0 + 32 * p + gcol;
                dst = &Bs[p][sb * 16][0] + lane * 8;
            }
            gload_lds16(src, dst);
        }
        __syncthreads();

        bf16x8 af[2][WR], bfr[2][WC];
#pragma unroll
        for (int p = 0; p < 2; p++) {
#pragma unroll
            for (int i = 0; i < WR; i++)
                af[p][i] = *(const bf16x8*)&As[p][wm * (BM / 2) + 16 * i + r16][quad * 8];
#pragma unroll
            for (int j = 0; j < WC; j++)
                bfr[p][j] = *(const bf16x8*)&Bs[p][wn * (BN / 2) + 16 * j + r16][quad * 8];
        }
#pragma unroll
        for (int p = 0; p < 2; p++)
#pragma unroll
            for (int i = 0; i < WR; i++)
#pragma unroll
                for (int j = 0; j < WC; j++)
                    acc[i][j] = __builtin_amdgcn_mfma_f32_16x16x32_bf16(af[p][i], bfr[p][j], acc[i][j], 0, 0, 0);
    }

    const int mask = (1 << epi.shift) - 1;
#pragma unroll
    for (int j = 0; j < WC; j++) {
        const int colb = n0 + wn * (BN / 2) + 16 * j;
        const int sel = __builtin_amdgcn_readfirstlane(colb >> epi.shift);
        const int lcol = (colb & mask) + r16;
        const int ldw = mask + 1;
        const float bv = epi.bias[sel] ? epi.bias[sel][lcol] : 0.0f;
        const float sc = epi.scale[sel];
        bf16* ob = epi.outB[sel];
        float* of = epi.outF[sel];
#pragma unroll
        for (int i = 0; i < WR; i++) {
            const int rowb = m0 + wm * (BM / 2) + 16 * i + 4 * quad;
#pragma unroll
            for (int e = 0; e < 4; e++) {
                float v = (acc[i][j][e] + bv) * sc;
                if (epi.relu) v = fmaxf(v, 0.0f);
                const size_t idx = (size_t)(rowb + e) * ldw + lcol;
                if (of) of[idx] = v;
                if (ob) ob[idx] = __float2bfloat16(v);
            }
        }
    }
}

// ---------------------------------------------------------------------------
// Flash attention — ROUND-8 structure restored (measured 64.3 us, the best of
// r8=64.3 / r9=67.2 (+K-prefetch, regressed) / r11=70.2 (4-way split,
// regressed)). 256 thr, 2-way key split across wave-pairs, Ps LDS round-trip,
// packed bf16 cvt, alpha-rescale skip.
// ROUND-12 addition: causal q-tile REVERSAL — self-attn work is 1..32 chunks
// per q-tile; ascending dispatch starts heavy tiles last (tail-bound). Map
// blockIdx.x -> heaviest-first when causal. Pure remap, no correctness risk.
// ---------------------------------------------------------------------------
#define PST 72  // LDS row stride (bf16): 64 + 8, keeps b128 alignment

__launch_bounds__(256)
__global__ void attn_mfma(const bf16* __restrict__ Qh, const bf16* __restrict__ Kh,
                          const bf16* __restrict__ Vh,
                          float* __restrict__ outF, bf16* __restrict__ outB,
                          int causal)
{
    __shared__ alignas(16) bf16 Vt[2][64][PST];    // per-pair [d][key]
    __shared__ alignas(16) bf16 Ps[4][32][PST];    // per-wave [q][key]
    __shared__ float Msh[2][64][34];               // merge scratch

    const int t = threadIdx.x;        // 0..255
    const int w = t >> 6;
    const int lane = t & 63;
    const int c32 = lane & 31;
    const int hi = lane >> 5;
    const int pair = t >> 7;
    const int qg = w & 1;
    const int pl = t & 127;
    const int bh = blockIdx.y;
    const int b = bh >> 3, h = bh & 7;
    // causal: reverse so the heavy (large-q0) tiles launch first
    const int bx = causal ? (gridDim.x - 1 - blockIdx.x) : blockIdx.x;
    const int q0 = bx * 64;
    const size_t rowbase = (size_t)b * S_LEN;
    const int hoff = h * DKH;

    bf16x8 qf[4];
    {
        const bf16* qp = Qh + (rowbase + q0 + 32 * qg + c32) * DMODEL + hoff + 8 * hi;
#pragma unroll
        for (int tt = 0; tt < 4; tt++) qf[tt] = *(const bf16x8*)(qp + 16 * tt);
    }

    floatx16 o0, o1;
#pragma unroll
    for (int e = 0; e < 16; e++) { o0[e] = 0.0f; o1[e] = 0.0f; }
    float m = -3e38f, l = 0.0f;

    const int rq = pl & 15;
    const int c8 = ((pl >> 4) & 7) * 8;

    const int nchunk = causal ? (q0 / 64 + 1) : (S_LEN / 64);
    const int nIter = (nchunk + 1) >> 1;

    for (int it = 0; it < nIter; it++) {
        const int ch = 2 * it + pair;
        const bool active = ch < nchunk;
        const int kb = ch * 64;
        __syncthreads();
        if (active) {      // stage V transposed (packed b64 writes)
            union { uint4 u; unsigned short s[8]; } r0, r1, r2, r3;
            const bf16* vb = Vh + (rowbase + kb + 4 * rq) * DMODEL + hoff + c8;
            r0.u = *(const uint4*)(vb);
            r1.u = *(const uint4*)(vb + DMODEL);
            r2.u = *(const uint4*)(vb + 2 * DMODEL);
            r3.u = *(const uint4*)(vb + 3 * DMODEL);
#pragma unroll
            for (int j = 0; j < 8; j++) {
                ushort4 pk = { r0.s[j], r1.s[j], r2.s[j], r3.s[j] };
                *(ushort4*)&Vt[pair][c8 + j][4 * rq] = pk;
            }
        }

        if (active) {
            floatx16 s0, s1;
#pragma unroll
            for (int e = 0; e < 16; e++) { s0[e] = 0.0f; s1[e] = 0.0f; }
            const bf16* kp = Kh + (rowbase + kb + c32) * DMODEL + hoff + 8 * hi;
#pragma unroll
            for (int tt = 0; tt < 4; tt++) {
                const bf16x8 k0 = *(const bf16x8*)(kp + 16 * tt);
                const bf16x8 k1 = *(const bf16x8*)(kp + (size_t)32 * DMODEL + 16 * tt);
                s0 = __builtin_amdgcn_mfma_f32_32x32x16_bf16(k0, qf[tt], s0, 0, 0, 0);
                s1 = __builtin_amdgcn_mfma_f32_32x32x16_bf16(k1, qf[tt], s1, 0, 0, 0);
            }

            if (causal && kb == q0) {
                const int qq = 32 * qg + c32;
#pragma unroll
                for (int r = 0; r < 16; r++) {
                    const int kl = (r & 3) + 8 * (r >> 2) + 4 * hi;
                    if (kl > qq) s0[r] = -3e38f;
                    if (kl + 32 > qq) s1[r] = -3e38f;
                }
            }

            float mc = -3e38f;
#pragma unroll
            for (int r = 0; r < 16; r++) mc = fmaxf(mc, fmaxf(s0[r], s1[r]));
            mc = fmaxf(mc, __shfl_xor(mc, 32, 64));
            const float mold = m;
            const float mn = fmaxf(m, mc);
            const float alpha = __expf(mold - mn);
            m = mn;

            float lc = 0.0f;
#pragma unroll
            for (int g = 0; g < 4; g++) {
                float p0 = __expf(s0[4 * g + 0] - mn), p1 = __expf(s0[4 * g + 1] - mn);
                float p2 = __expf(s0[4 * g + 2] - mn), p3 = __expf(s0[4 * g + 3] - mn);
                lc += (p0 + p1) + (p2 + p3);
                uint2 pw; pw.x = pk2(p0, p1); pw.y = pk2(p2, p3);
                *(uint2*)&Ps[w][c32][8 * g + 4 * hi] = pw;
                p0 = __expf(s1[4 * g + 0] - mn); p1 = __expf(s1[4 * g + 1] - mn);
                p2 = __expf(s1[4 * g + 2] - mn); p3 = __expf(s1[4 * g + 3] - mn);
                lc += (p0 + p1) + (p2 + p3);
                uint2 pw1; pw1.x = pk2(p0, p1); pw1.y = pk2(p2, p3);
                *(uint2*)&Ps[w][c32][32 + 8 * g + 4 * hi] = pw1;
            }
            lc += __shfl_xor(lc, 32, 64);
            l = l * alpha + lc;

            // O-rescale only if some lane's running max moved
            if (!__all(mn == mold)) {
#pragma unroll
                for (int r = 0; r < 16; r++) {
                    const float a = __shfl(alpha, (r & 3) + 8 * (r >> 2) + 4 * hi, 64);
                    o0[r] *= a; o1[r] *= a;
                }
            }
        }

        __syncthreads();

        if (active) {
#pragma unroll
            for (int tt = 0; tt < 4; tt++) {
                const bf16x8 pf = *(const bf16x8*)&Ps[w][c32][16 * tt + 8 * hi];
                const bf16x8 v0 = *(const bf16x8*)&Vt[pair][c32][16 * tt + 8 * hi];
                const bf16x8 v1 = *(const bf16x8*)&Vt[pair][32 + c32][16 * tt + 8 * hi];
                o0 = __builtin_amdgcn_mfma_f32_32x32x16_bf16(pf, v0, o0, 0, 0, 0);
                o1 = __builtin_amdgcn_mfma_f32_32x32x16_bf16(pf, v1, o1, 0, 0, 0);
            }
        }
    }

    // ---- split-KV merge: pair1 -> LDS, pair0 combines & writes ----
    __syncthreads();
    if (pair == 1) {
        float* dst = &Msh[qg][lane][0];
        dst[0] = m; dst[1] = l;
#pragma unroll
        for (int r = 0; r < 16; r++) { dst[2 + r] = o0[r]; dst[18 + r] = o1[r]; }
    }
    __syncthreads();
    if (pair == 0) {
        const float* src = &Msh[qg][lane][0];
        const float m_b = src[0], l_b = src[1];
        const float mt = fmaxf(m, m_b);
        const float sA = __expf(m - mt);
        const float sB = __expf(m_b - mt);
        const float lt = l * sA + l_b * sB;
#pragma unroll
        for (int r = 0; r < 16; r++) {
            const int ql = (r & 3) + 8 * (r >> 2) + 4 * hi;
            const float sAr = __shfl(sA, ql, 64);
            const float sBr = __shfl(sB, ql, 64);
            const float li = 1.0f / __shfl(lt, ql, 64);
            const float v0 = (o0[r] * sAr + src[2 + r] * sBr) * li;
            const float v1 = (o1[r] * sAr + src[18 + r] * sBr) * li;
            const size_t idx = (rowbase + q0 + 32 * qg + ql) * DMODEL + hoff + c32;
            if (outF) { outF[idx] = v0; outF[idx + 32] = v1; }
            if (outB) { outB[idx] = __float2bfloat16(v0); outB[idx + 32] = __float2bfloat16(v1); }
        }
    }
}

// ---------------------------------------------------------------------------
// Fused residual + LayerNorm over D=512. One WG (256 thr) per row.
// ---------------------------------------------------------------------------
__launch_bounds__(256)
__global__ void ln_kernel(const float* __restrict__ xmain,
                          const float* __restrict__ resF, const bf16* __restrict__ resB,
                          const float* __restrict__ g, const float* __restrict__ bb,
                          float* __restrict__ outF, bf16* __restrict__ outB)
{
    const int row = blockIdx.x;
    const int t = threadIdx.x;
    const size_t base = (size_t)row * DMODEL;

    float x0 = xmain[base + t];
    float x1 = xmain[base + t + 256];
    if (resF) { x0 += resF[base + t]; x1 += resF[base + t + 256]; }
    if (resB) { x0 += __bfloat162float(resB[base + t]); x1 += __bfloat162float(resB[base + t + 256]); }

    __shared__ float sred[4];
    float s = x0 + x1;
#pragma unroll
    for (int off = 32; off > 0; off >>= 1) s += __shfl_down(s, off);
    if ((t & 63) == 0) sred[t >> 6] = s;
    __syncthreads();
    const float mu = (sred[0] + sred[1] + sred[2] + sred[3]) * (1.0f / DMODEL);

    const float d0 = x0 - mu, d1 = x1 - mu;
    float sv = d0 * d0 + d1 * d1;
#pragma unroll
    for (int off = 32; off > 0; off >>= 1) sv += __shfl_down(sv, off);
    __syncthreads();
    if ((t & 63) == 0) sred[t >> 6] = sv;
    __syncthreads();
    const float var = (sred[0] + sred[1] + sred[2] + sred[3]) * (1.0f / DMODEL);
    const float rstd = rsqrtf(var + 1e-5f);

    const float y0 = d0 * rstd * g[t] + bb[t];
    const float y1 = d1 * rstd * g[t + 256] + bb[t + 256];
    if (outF) { outF[base + t] = y0; outF[base + t + 256] = y1; }
    if (outB) { outB[base + t] = __float2bfloat16(y0); outB[base + t + 256] = __float2bfloat16(y1); }
}

// ---------------------------------------------------------------------------
// Workspace layout (55.5 MB) — see round 5 comment.
// ---------------------------------------------------------------------------
extern "C" void kernel_launch(void* const* d_in, const int* in_sizes, int n_in,
                              void* d_out, int out_size, void* d_ws, size_t ws_size,
                              hipStream_t stream)
{
    const float* x_q       = (const float*)d_in[0];
    const float* x1        = (const float*)d_in[1];
    const float* x2        = (const float*)d_in[2];
    const float* sa_wq     = (const float*)d_in[3];
    const float* sa_bq     = (const float*)d_in[4];
    const float* sa_wk     = (const float*)d_in[5];
    const float* sa_bk     = (const float*)d_in[6];
    const float* sa_wv     = (const float*)d_in[7];
    const float* sa_bv     = (const float*)d_in[8];
    const float* ln1_g     = (const float*)d_in[9];
    const float* ln1_b     = (const float*)d_in[10];
    const float* mha_in_w  = (const float*)d_in[11];
    const float* mha_in_b  = (const float*)d_in[12];
    const float* mha_out_w = (const float*)d_in[13];
    const float* mha_out_b = (const float*)d_in[14];
    const float* ln2_g     = (const float*)d_in[15];
    const float* ln2_b     = (const float*)d_in[16];
    const float* ffn_w1    = (const float*)d_in[17];
    const float* ffn_b1    = (const float*)d_in[18];
    const float* ffn_w2    = (const float*)d_in[19];
    const float* ffn_b2    = (const float*)d_in[20];
    const float* ln3_g     = (const float*)d_in[21];
    const float* ln3_b     = (const float*)d_in[22];

    char* ws = (char*)d_ws;
    const size_t MB = 1024 * 1024;
    const size_t KB = 1024;
    bf16*  q16  = (bf16*)(ws + 0 * MB);
    bf16*  k16  = (bf16*)(ws + 4 * MB);
    bf16*  v16  = (bf16*)(ws + 8 * MB);
    bf16*  a16  = (bf16*)(ws + 12 * MB);
    float* tmp  = (float*)(ws + 16 * MB);
    bf16*  y16  = (bf16*)(ws + 24 * MB);
    bf16*  ya16 = (bf16*)(ws + 28 * MB);
    bf16*  ya2  = (bf16*)(ws + 32 * MB);
    bf16*  xq16 = (bf16*)(ws + 36 * MB);
    bf16*  x116 = (bf16*)(ws + 40 * MB);
    bf16*  x216 = (bf16*)(ws + 44 * MB);
    bf16*  w_sa_qkv = (bf16*)(ws + 48 * MB);            // 1.5 MB (3D x D contig)
    bf16*  w_in   = (bf16*)(ws + 49 * MB + 512 * KB);   // 1.5 MB
    bf16*  w_out  = (bf16*)(ws + 51 * MB);              // 0.5 MB
    bf16*  w_f1   = (bf16*)(ws + 51 * MB + 512 * KB);   // 2 MB
    bf16*  w_f2   = (bf16*)(ws + 53 * MB + 512 * KB);   // 2 MB
    bf16*  h16    = (bf16*)(ws + 0 * MB);               // aliases q..a (dead by FFN)

    const int DD = DMODEL * DMODEL;
    CvtDesc cd;
    cd.seg[0]  = { x_q,       xq16,        (NROWS * DMODEL) / 4 };
    cd.seg[1]  = { x1,        x116,        (NROWS * DMODEL) / 4 };
    cd.seg[2]  = { x2,        x216,        (NROWS * DMODEL) / 4 };
    cd.seg[3]  = { sa_wq,     w_sa_qkv,           DD / 4 };
    cd.seg[4]  = { sa_wk,     w_sa_qkv + DD,      DD / 4 };
    cd.seg[5]  = { sa_wv,     w_sa_qkv + 2 * DD,  DD / 4 };
    cd.seg[6]  = { mha_in_w,  w_in,   3 * DD / 4 };
    cd.seg[7]  = { mha_out_w, w_out,  DD / 4 };
    cd.seg[8]  = { ffn_w1,    w_f1,   (FFDIM * DMODEL) / 4 };
    cd.seg[9]  = { ffn_w2,    w_f2,   (FFDIM * DMODEL) / 4 };
    cd.seg[10] = { x_q,       xq16,   0 };
    cd.seg[11] = { x_q,       xq16,   0 };
    cvt_f32_bf16<<<dim3(64, 10), 256, 0, stream>>>(cd);

    const dim3 blk(256);
    const dim3 agrid(S_LEN / 64, BATCH * NHEAD);   // (32,16) = 512 WGs

    Epi eQKV = {};   // self Q/K/V fused, N=1536 -> q16|k16|v16
    eQKV.outB[0] = q16; eQKV.outB[1] = k16; eQKV.outB[2] = v16;
    eQKV.bias[0] = sa_bq; eQKV.bias[1] = sa_bk; eQKV.bias[2] = sa_bv;
    eQKV.scale[0] = 0.125f; eQKV.scale[1] = 1.0f; eQKV.scale[2] = 1.0f;
    eQKV.shift = 9;

    Epi eX1 = {};    // cross1 Q|K|V fused, N=1536; A=y16 (slab0), A2=x116 (slabs 1-2)
    eX1.outB[0] = q16; eX1.outB[1] = k16; eX1.outB[2] = v16;
    eX1.bias[0] = mha_in_b; eX1.bias[1] = mha_in_b + DMODEL; eX1.bias[2] = mha_in_b + 2 * DMODEL;
    eX1.scale[0] = 0.125f; eX1.scale[1] = 1.0f; eX1.scale[2] = 1.0f;
    eX1.A2 = x116; eX1.a2slab = 1; eX1.shift = 9;

    Epi eX2 = eX1;   // cross2: A=ya16, A2=x216
    eX2.A2 = x216;

    Epi eOut = {};   // out-proj, N=512 -> tmp (fp32)
    eOut.outF[0] = tmp; eOut.bias[0] = mha_out_b; eOut.scale[0] = 1.0f; eOut.shift = 9;

    Epi eF1 = {};    // FFN1, N=2048 -> h16, relu
    eF1.outB[0] = h16; eF1.bias[0] = ffn_b1; eF1.scale[0] = 1.0f;
    eF1.shift = 11; eF1.relu = 1;

    Epi eF2 = {};    // FFN2, N=512 -> tmp (fp32)
    eF2.outF[0] = tmp; eF2.bias[0] = ffn_b2; eF2.scale[0] = 1.0f; eF2.shift = 9;

    // ---- self attention (causal, no out-proj) ----
    gemm2<64, 64><<<dim3(64, 24), blk, 0, stream>>>(xq16, w_sa_qkv, eQKV, DMODEL);
    attn_mfma<<<agrid, blk, 0, stream>>>(q16, k16, v16, tmp, nullptr, 1);
    ln_kernel<<<NROWS, blk, 0, stream>>>(tmp, x_q, nullptr, ln1_g, ln1_b, nullptr, y16);

    // ---- cross attention 1: q from y, k/v from x1 (one fused GEMM) ----
    gemm2<64, 64><<<dim3(64, 24), blk, 0, stream>>>(y16, w_in, eX1, DMODEL);
    attn_mfma<<<agrid, blk, 0, stream>>>(q16, k16, v16, nullptr, a16, 0);
    gemm2<64, 64><<<dim3(64, 8), blk, 0, stream>>>(a16, w_out, eOut, DMODEL);
    ln_kernel<<<NROWS, blk, 0, stream>>>(tmp, nullptr, y16, ln2_g, ln2_b, nullptr, ya16);

    // ---- cross attention 2: q from yattn, k/v from x2 ----
    gemm2<64, 64><<<dim3(64, 24), blk, 0, stream>>>(ya16, w_in, eX2, DMODEL);
    attn_mfma<<<agrid, blk, 0, stream>>>(q16, k16, v16, nullptr, a16, 0);
    gemm2<64, 64><<<dim3(64, 8), blk, 0, stream>>>(a16, w_out, eOut, DMODEL);
    ln_kernel<<<NROWS, blk, 0, stream>>>(tmp, nullptr, ya16, ln2_g, ln2_b, nullptr, ya2);

    // ---- FFN ----
    gemm2<128, 128><<<dim3(32, 16), blk, 0, stream>>>(ya2, w_f1, eF1, DMODEL);
    gemm2<64, 64><<<dim3(64, 8), blk, 0, stream>>>(h16, w_f2, eF2, FFDIM);
    ln_kernel<<<NROWS, blk, 0, stream>>>(tmp, nullptr, ya2, ln3_g, ln3_b, (float*)d_out, nullptr);
}